// Round 5
// baseline (121.723 us; speedup 1.0000x reference)
//
#include <hip/hip_runtime.h>

#define S 512
#define H 128
#define NROW 4096   // B*S
#define TI 8

typedef _Float16 h2v __attribute__((ext_vector_type(2)));
#define BCH(x) __builtin_bit_cast(h2v, (x))

static __device__ __forceinline__ unsigned pkh(float a, float b) {
  h2v p; p.x = (_Float16)a; p.y = (_Float16)b;   // RNE casts
  return __builtin_bit_cast(unsigned, p);
}

// ---------------- kernel 1: projections + fp16 packing ----------------
// blocks 0..511: query rows -> qph ; 512..1023: key rows -> kph ;
// 1024..1279: value -> vph (fp32 -> fp16x2 convert, 8 floats/thread).
// Dead q-rows (q_mask==0) skip compute/store: qp never read for them.
__global__ __launch_bounds__(256) void proj_kernel(
    const float* __restrict__ query, const float* __restrict__ key,
    const float* __restrict__ value,
    const float* __restrict__ W1, const float* __restrict__ b1,
    const float* __restrict__ W2, const int* __restrict__ q_mask,
    unsigned* __restrict__ qph, unsigned* __restrict__ kph,
    unsigned* __restrict__ vph, unsigned* __restrict__ w2h)
{
  __shared__ float w1t[64][130];    // w1t[d][h] = W1[h][off + p*64 + d]
  const int bid = blockIdx.x;       // 0..1279
  const int tid = threadIdx.x;

  if (bid >= 1024) {                // ---- value fp16 convert ----
    const int base = (bid - 1024) * 2048 + tid * 8;   // float index
    const float4 v0 = *(const float4*)(value + base);
    const float4 v1 = *(const float4*)(value + base + 4);
    uint4 o;
    o.x = pkh(v0.x, v0.y); o.y = pkh(v0.z, v0.w);
    o.z = pkh(v1.x, v1.y); o.w = pkh(v1.z, v1.w);
    *(uint4*)(vph + (base >> 1)) = o;
    return;
  }

  const bool isq = bid < 512;
  const float* __restrict__ src = isq ? query : key;
  const int rbase = (isq ? bid : bid - 512) * 8;
  const int off = isq ? 0 : 128;

  if (bid == 0 && tid < 64) {       // pack W2 -> half2 once
    w2h[tid] = pkh(W2[2 * tid], W2[2 * tid + 1]);
  }

  const int w = __builtin_amdgcn_readfirstlane(tid >> 6);   // 0..3
  const int lane = tid & 63;
  const int r0 = rbase + w * 2;     // 2 rows per wave

  int live[2] = {1, 1};             // key rows always live
  if (isq) { live[0] = q_mask[r0]; live[1] = q_mask[r0 + 1]; }

  float acc[2][2];
  float2 bv = make_float2(0.f, 0.f);
  if (isq) bv = *(const float2*)(b1 + 2 * lane);
  acc[0][0] = bv.x; acc[0][1] = bv.y;
  acc[1][0] = bv.x; acc[1][1] = bv.y;

  for (int p = 0; p < 2; p++) {     // two 64-wide d passes (33 KB LDS)
    for (int idx = tid; idx < 128 * 16; idx += 256) {
      const int d4 = idx & 15, h = idx >> 4;
      const float4 v = *(const float4*)(W1 + h * 256 + off + p * 64 + d4 * 4);
      w1t[d4 * 4 + 0][h] = v.x;
      w1t[d4 * 4 + 1][h] = v.y;
      w1t[d4 * 4 + 2][h] = v.z;
      w1t[d4 * 4 + 3][h] = v.w;
    }
    __syncthreads();

    if (live[0] | live[1]) {
      for (int dc = 0; dc < 64; dc += 8) {
        float qs[2][8];             // wave-uniform -> s_load
        #pragma unroll
        for (int r = 0; r < 2; r++) {
          if (live[r]) {            // uniform branch
            const float* sp = src + (size_t)(r0 + r) * H + p * 64 + dc;
            #pragma unroll
            for (int u = 0; u < 8; u++) qs[r][u] = sp[u];
          }
        }
        #pragma unroll
        for (int dd = 0; dd < 8; dd++) {
          const float2 wv = *(const float2*)&w1t[dc + dd][2 * lane];
          #pragma unroll
          for (int r = 0; r < 2; r++) {
            if (live[r]) {
              acc[r][0] = __builtin_fmaf(qs[r][dd], wv.x, acc[r][0]);
              acc[r][1] = __builtin_fmaf(qs[r][dd], wv.y, acc[r][1]);
            }
          }
        }
      }
    }
    __syncthreads();                // before restaging w1t
  }

  unsigned* __restrict__ dst = isq ? qph : kph;
  #pragma unroll
  for (int r = 0; r < 2; r++)
    if (live[r])
      dst[(size_t)(r0 + r) * 64 + lane] = pkh(acc[r][0], acc[r][1]);
}

// ---------------- kernel 2: fused scores + exp + AV + normalize ----------
// 512 blocks x 512 thr (8 waves). Block = (b, i-tile of TI=8 rows), full
// j-range 512 in-block (wave w owns j = w*64+lane) -> writes out directly.
// a bounced through LDS as packed fp16 (1 ds_read_b128 = all 8 a-values);
// phase-2 MACs use f16 sources with f32 accum (v_fma_mix via mad-mix fold).
__global__ __launch_bounds__(512, 4) void attn_kernel(
    const unsigned* __restrict__ qph, const unsigned* __restrict__ kph,
    const unsigned* __restrict__ w2h, const unsigned* __restrict__ vph,
    const int* __restrict__ q_mask, const int* __restrict__ k_mask,
    const float* __restrict__ b2, float* __restrict__ out)
{
  union __align__(16) SMU {
    unsigned aTp[8][64][4];         // per-wave packed a (8 fp16 per lane)
    float numk[8][TI][132];         // per-wave num partials (after barrier)
  };
  __shared__ SMU sm;
  __shared__ float denk[8][TI];

  const int bid = blockIdx.x;                    // 0..511
  const int it = (bid & 7) * 64 + (bid >> 3);    // bijective XCD swizzle
  const int r0 = it * TI;                        // q-row base (uniform)
  const int b = r0 >> 9;                         // == bid & 7
  const int tid = threadIdx.x;
  const int w = __builtin_amdgcn_readfirstlane(tid >> 6);   // 0..7
  const int lane = tid & 63;
  const int jl = (w << 6) + lane;   // within-b key index 0..511
  const int jg = (b << 9) + jl;     // global key row
  const int km = k_mask[jg];
  const unsigned* __restrict__ kprow = kph + (size_t)jg * 64;
  const float b2v = b2[0];
  const h2v hz = {};

  int qmv[TI];
  int anyq = 0;
  #pragma unroll
  for (int i = 0; i < TI; i++) { qmv[i] = q_mask[r0 + i]; anyq |= qmv[i]; }

  // ---- phase 1: s[i] for this lane's j (packed fp16, fp32 accum) ----
  float s[TI];
  #pragma unroll
  for (int i = 0; i < TI; i++) s[i] = 0.f;

  if (anyq) {
    for (int hc = 0; hc < 64; hc += 16) {   // 16 half2 = 32 h per chunk
      h2v kr[16];
      {
        const uint4* k4 = (const uint4*)(kprow + hc);
        const uint4 a0 = k4[0], a1 = k4[1], a2 = k4[2], a3 = k4[3];
        kr[0]  = BCH(a0.x); kr[1]  = BCH(a0.y); kr[2]  = BCH(a0.z); kr[3]  = BCH(a0.w);
        kr[4]  = BCH(a1.x); kr[5]  = BCH(a1.y); kr[6]  = BCH(a1.z); kr[7]  = BCH(a1.w);
        kr[8]  = BCH(a2.x); kr[9]  = BCH(a2.y); kr[10] = BCH(a2.z); kr[11] = BCH(a2.w);
        kr[12] = BCH(a3.x); kr[13] = BCH(a3.y); kr[14] = BCH(a3.z); kr[15] = BCH(a3.w);
      }
      h2v w2c[16];                    // uniform -> SGPRs
      #pragma unroll
      for (int u = 0; u < 16; u++) w2c[u] = BCH(w2h[hc + u]);

      #pragma unroll
      for (int i = 0; i < TI; i++) {
        if (qmv[i]) {                 // uniform branch: dead rows skipped
          const unsigned* __restrict__ qrow =
              qph + (size_t)(r0 + i) * 64 + hc;   // uniform -> s_load batch
          unsigned qu[16];
          #pragma unroll
          for (int u = 0; u < 16; u++) qu[u] = qrow[u];
          #pragma unroll
          for (int u = 0; u < 16; u++) {
            h2v t = BCH(qu[u]) + kr[u];                    // v_pk_add_f16
            t = __builtin_elementwise_max(t, hz);          // v_pk_max_f16
            s[i] = __builtin_amdgcn_fdot2(t, w2c[u], s[i], false); // v_dot2_f32_f16
          }
        }
      }
    }
  }

  // ---- mask + exp + intra-wave den reduce (skipped for dead rows) ----
  float a[TI];
  #pragma unroll
  for (int i = 0; i < TI; i++) {
    if (qmv[i]) {
      a[i] = (km > 0) ? __expf(s[i] + b2v) : 0.f;
      float d = a[i];
      #pragma unroll
      for (int m = 32; m >= 1; m >>= 1) d += __shfl_xor(d, m, 64);
      if (lane == 0) denk[w][i] = d;
    } else {
      a[i] = 0.f;
      if (lane == 0) denk[w][i] = 0.f;
    }
  }
  {
    uint4 apk;
    apk.x = pkh(a[0], a[1]); apk.y = pkh(a[2], a[3]);
    apk.z = pkh(a[4], a[5]); apk.w = pkh(a[6], a[7]);
    *(uint4*)&sm.aTp[w][lane][0] = apk;
  }
  __syncthreads();

  // ---- phase 2: num[i][h] += a[i][j]*v[j][h] over this wave's 64 j ----
  const int lj = lane >> 5, lh = lane & 31;   // lj: j-parity, lh*4: h window
  float nr[TI][4];
  #pragma unroll
  for (int i = 0; i < TI; i++) { nr[i][0]=0.f; nr[i][1]=0.f; nr[i][2]=0.f; nr[i][3]=0.f; }
  const unsigned* __restrict__ vbase =
      vph + ((size_t)b * S + (w << 6)) * 64;  // fp16x2 rows, 64 u32 each

  if (anyq) {
    #pragma unroll 4
    for (int js = 0; js < 32; js++) {
      const int j = js * 2 + lj;
      const uint4 ap = *(const uint4*)&sm.aTp[w][j][0];   // all 8 a (fp16)
      const uint2 vv = *(const uint2*)(vbase + (size_t)j * 64 + lh * 2);
      const h2v a01 = BCH(ap.x), a23 = BCH(ap.y);
      const h2v a45 = BCH(ap.z), a67 = BCH(ap.w);
      const h2v pv0 = BCH(vv.x), pv1 = BCH(vv.y);
      const _Float16 ah[TI] = {a01.x, a01.y, a23.x, a23.y,
                               a45.x, a45.y, a67.x, a67.y};
      const _Float16 vh[4] = {pv0.x, pv0.y, pv1.x, pv1.y};
      #pragma unroll
      for (int i = 0; i < TI; i++) {
        #pragma unroll
        for (int k = 0; k < 4; k++)
          nr[i][k] = __builtin_fmaf((float)ah[i], (float)vh[k], nr[i][k]);
      }
    }
    #pragma unroll
    for (int i = 0; i < TI; i++) {
      #pragma unroll
      for (int k = 0; k < 4; k++) nr[i][k] += __shfl_xor(nr[i][k], 32, 64);
    }
  }

  __syncthreads();   // all aTp reads done before numk overwrites the union
  if (lane < 32) {   // lh == lane; both j-parities hold the folded sum
    #pragma unroll
    for (int i = 0; i < TI; i++)
      *(float4*)&sm.numk[w][i][lane * 4] =
          make_float4(nr[i][0], nr[i][1], nr[i][2], nr[i][3]);
  }
  __syncthreads();

  // ---- cross-wave reduce + normalize + store out directly ----
  const int ii = tid >> 6;              // 0..7 (wave-uniform)
  const int h0 = tid & 63;              // two h per thread: h0, h0+64
  float n0 = 0.f, n1 = 0.f, d = 0.f;
  #pragma unroll
  for (int ww = 0; ww < 8; ww++) {
    n0 += sm.numk[ww][ii][h0];
    n1 += sm.numk[ww][ii][h0 + 64];
    d += denk[ww][ii];
  }
  const float inv = 1.f / fmaxf(d, 2e-15f);
  out[(size_t)(r0 + ii) * H + h0] = n0 * inv;
  out[(size_t)(r0 + ii) * H + h0 + 64] = n1 * inv;
}

extern "C" void kernel_launch(void* const* d_in, const int* in_sizes, int n_in,
                              void* d_out, int out_size, void* d_ws, size_t ws_size,
                              hipStream_t stream)
{
  (void)in_sizes; (void)n_in; (void)out_size; (void)ws_size;
  const float* query  = (const float*)d_in[0];
  const float* key    = (const float*)d_in[1];
  const float* value  = (const float*)d_in[2];
  const int*   q_mask = (const int*)d_in[3];
  const int*   k_mask = (const int*)d_in[4];
  const float* W1     = (const float*)d_in[5];
  const float* b1     = (const float*)d_in[6];
  const float* W2     = (const float*)d_in[7];
  const float* b2     = (const float*)d_in[8];
  float* out = (float*)d_out;

  unsigned* ws  = (unsigned*)d_ws;
  unsigned* qph = ws;                                // [4096][64] half2
  unsigned* kph = ws + (size_t)NROW * 64;            // [4096][64] half2
  unsigned* vph = kph + (size_t)NROW * 64;           // [4096][64] half2
  unsigned* w2h = vph + (size_t)NROW * 64;           // [64] half2

  proj_kernel<<<1280, 256, 0, stream>>>(query, key, value, W1, b1, W2, q_mask,
                                        qph, kph, vph, w2h);
  attn_kernel<<<512, 512, 0, stream>>>(qph, kph, w2h, vph, q_mask, k_mask,
                                       b2, out);
}

// Round 6
// 104.576 us; speedup vs baseline: 1.1640x; 1.1640x over previous
//
#include <hip/hip_runtime.h>

#define S 512
#define H 128
#define NROW 4096   // B*S
#define TI 8

typedef _Float16 h2v __attribute__((ext_vector_type(2)));
#define BCH(x) __builtin_bit_cast(h2v, (x))

static __device__ __forceinline__ unsigned pkh(float a, float b) {
  h2v p; p.x = (_Float16)a; p.y = (_Float16)b;   // RNE casts
  return __builtin_bit_cast(unsigned, p);
}

// ---------------- kernel 1: projections + fp16 packing (R4-exact) --------
// blocks 0..511: query rows -> qph ; 512..1023: key rows -> kph ;
// 1024..1279: value -> vph (fp32 -> fp16x2 convert, 8 floats/thread).
__global__ __launch_bounds__(256) void proj_kernel(
    const float* __restrict__ query, const float* __restrict__ key,
    const float* __restrict__ value,
    const float* __restrict__ W1, const float* __restrict__ b1,
    const float* __restrict__ W2,
    unsigned* __restrict__ qph, unsigned* __restrict__ kph,
    unsigned* __restrict__ vph, unsigned* __restrict__ w2h)
{
  __shared__ float w1t[64][130];    // w1t[d][h] = W1[h][off + p*64 + d]
  const int bid = blockIdx.x;       // 0..1279
  const int tid = threadIdx.x;

  if (bid >= 1024) {                // ---- value fp16 convert ----
    const int base = (bid - 1024) * 2048 + tid * 8;   // float index
    const float4 v0 = *(const float4*)(value + base);
    const float4 v1 = *(const float4*)(value + base + 4);
    uint4 o;
    o.x = pkh(v0.x, v0.y); o.y = pkh(v0.z, v0.w);
    o.z = pkh(v1.x, v1.y); o.w = pkh(v1.z, v1.w);
    *(uint4*)(vph + (base >> 1)) = o;
    return;
  }

  const bool isq = bid < 512;
  const float* __restrict__ src = isq ? query : key;
  const int rbase = (isq ? bid : bid - 512) * 8;
  const int off = isq ? 0 : 128;

  if (bid == 0 && tid < 64) {       // pack W2 -> half2 once
    w2h[tid] = pkh(W2[2 * tid], W2[2 * tid + 1]);
  }

  const int w = __builtin_amdgcn_readfirstlane(tid >> 6);   // 0..3
  const int lane = tid & 63;
  const int r0 = rbase + w * 2;     // 2 rows per wave

  float acc[2][2];
  float2 bv = make_float2(0.f, 0.f);
  if (isq) bv = *(const float2*)(b1 + 2 * lane);
  acc[0][0] = bv.x; acc[0][1] = bv.y;
  acc[1][0] = bv.x; acc[1][1] = bv.y;

  for (int p = 0; p < 2; p++) {     // two 64-wide d passes (33 KB LDS)
    for (int idx = tid; idx < 128 * 16; idx += 256) {
      const int d4 = idx & 15, h = idx >> 4;
      const float4 v = *(const float4*)(W1 + h * 256 + off + p * 64 + d4 * 4);
      w1t[d4 * 4 + 0][h] = v.x;
      w1t[d4 * 4 + 1][h] = v.y;
      w1t[d4 * 4 + 2][h] = v.z;
      w1t[d4 * 4 + 3][h] = v.w;
    }
    __syncthreads();

    for (int dc = 0; dc < 64; dc += 8) {
      float qs[2][8];               // wave-uniform -> s_load
      #pragma unroll
      for (int r = 0; r < 2; r++) {
        const float* sp = src + (size_t)(r0 + r) * H + p * 64 + dc;
        #pragma unroll
        for (int u = 0; u < 8; u++) qs[r][u] = sp[u];
      }
      #pragma unroll
      for (int dd = 0; dd < 8; dd++) {
        const float2 wv = *(const float2*)&w1t[dc + dd][2 * lane];
        #pragma unroll
        for (int r = 0; r < 2; r++) {
          acc[r][0] = __builtin_fmaf(qs[r][dd], wv.x, acc[r][0]);
          acc[r][1] = __builtin_fmaf(qs[r][dd], wv.y, acc[r][1]);
        }
      }
    }
    __syncthreads();                // before restaging w1t
  }

  unsigned* __restrict__ dst = isq ? qph : kph;
  #pragma unroll
  for (int r = 0; r < 2; r++)
    dst[(size_t)(r0 + r) * 64 + lane] = pkh(acc[r][0], acc[r][1]);
}

// ---------------- kernel 2: fused scores + exp + AV + normalize ----------
// 512 blocks x 512 thr (8 waves). Block = (b, i-tile of TI=8 rows).
// NEW: live-k compaction. Ballot-compact the ~50% live j's into jorig[];
// wave w handles compacted slots [w*64, w*64+64). Waves entirely past
// nlive skip phase 1 AND phase 2 via uniform branches. V-row gather via
// __shfl keeps loads coalesced (half-wave reads one V row).
__global__ __launch_bounds__(512, 4) void attn_kernel(
    const unsigned* __restrict__ qph, const unsigned* __restrict__ kph,
    const unsigned* __restrict__ w2h, const unsigned* __restrict__ vph,
    const int* __restrict__ q_mask, const int* __restrict__ k_mask,
    const float* __restrict__ b2, float* __restrict__ out)
{
  union __align__(16) SMU {
    float aT[8][64][12];            // per-wave a bounce (f32, R4 form)
    float numk[8][TI][132];         // per-wave num partials (after barrier)
  };
  __shared__ SMU sm;
  __shared__ float denk[8][TI];
  __shared__ unsigned long long bm[8];
  __shared__ unsigned short jorig[512];

  const int bid = blockIdx.x;                    // 0..511
  const int it = (bid & 7) * 64 + (bid >> 3);    // bijective XCD swizzle
  const int r0 = it * TI;                        // q-row base (uniform)
  const int b = r0 >> 9;                         // == bid & 7
  const int tid = threadIdx.x;
  const int w = __builtin_amdgcn_readfirstlane(tid >> 6);   // 0..7
  const int lane = tid & 63;
  const int jl = (w << 6) + lane;   // compacted slot index 0..511
  const float b2v = b2[0];
  const h2v hz = {};

  // ---- compact live k rows (deterministic: index order) ----
  const int kf = k_mask[(b << 9) + tid] > 0;
  const unsigned long long m = __ballot(kf);
  if (lane == 0) bm[w] = m;
  __syncthreads();
  int nlive = 0, basec = 0;
  #pragma unroll
  for (int x = 0; x < 8; x++) {
    const int c = __popcll(bm[x]);
    if (x < w) basec += c;          // uniform (w uniform)
    nlive += c;
  }
  if (kf) {
    const int pos = basec + __popcll(m & ((1ull << lane) - 1));
    jorig[pos] = (unsigned short)tid;
  }
  __syncthreads();

  const bool live = jl < nlive;                       // per-lane
  const bool wlive = (w << 6) < nlive;                // uniform per wave
  const int myj = live ? (int)jorig[jl] : 0;          // original j
  const unsigned* __restrict__ kprow = kph + (size_t)((b << 9) + myj) * 64;

  int qmv[TI];
  int anyq = 0;
  #pragma unroll
  for (int i = 0; i < TI; i++) { qmv[i] = q_mask[r0 + i]; anyq |= qmv[i]; }

  // ---- phase 1: s[i] for this lane's live j (packed fp16, fp32 accum) ----
  float s[TI];
  #pragma unroll
  for (int i = 0; i < TI; i++) s[i] = 0.f;

  if (anyq && wlive) {
    for (int hc = 0; hc < 64; hc += 16) {   // 16 half2 = 32 h per chunk
      h2v kr[16];
      {
        const uint4* k4 = (const uint4*)(kprow + hc);
        const uint4 a0 = k4[0], a1 = k4[1], a2 = k4[2], a3 = k4[3];
        kr[0]  = BCH(a0.x); kr[1]  = BCH(a0.y); kr[2]  = BCH(a0.z); kr[3]  = BCH(a0.w);
        kr[4]  = BCH(a1.x); kr[5]  = BCH(a1.y); kr[6]  = BCH(a1.z); kr[7]  = BCH(a1.w);
        kr[8]  = BCH(a2.x); kr[9]  = BCH(a2.y); kr[10] = BCH(a2.z); kr[11] = BCH(a2.w);
        kr[12] = BCH(a3.x); kr[13] = BCH(a3.y); kr[14] = BCH(a3.z); kr[15] = BCH(a3.w);
      }
      h2v w2c[16];                    // uniform -> SGPRs
      #pragma unroll
      for (int u = 0; u < 16; u++) w2c[u] = BCH(w2h[hc + u]);

      #pragma unroll
      for (int i = 0; i < TI; i++) {
        if (qmv[i]) {                 // uniform branch: dead rows skipped
          const unsigned* __restrict__ qrow =
              qph + (size_t)(r0 + i) * 64 + hc;   // uniform -> s_load batch
          unsigned qu[16];
          #pragma unroll
          for (int u = 0; u < 16; u++) qu[u] = qrow[u];
          #pragma unroll
          for (int u = 0; u < 16; u++) {
            h2v t = BCH(qu[u]) + kr[u];                    // v_pk_add_f16
            t = __builtin_elementwise_max(t, hz);          // v_pk_max_f16
            s[i] = __builtin_amdgcn_fdot2(t, w2c[u], s[i], false); // v_dot2_f32_f16
          }
        }
      }
    }
  }

  // ---- exp + intra-wave den reduce (dead rows / dead waves skipped) ----
  float a[TI];
  #pragma unroll
  for (int i = 0; i < TI; i++) {
    if (qmv[i] && wlive) {
      a[i] = live ? __expf(s[i] + b2v) : 0.f;
      float d = a[i];
      #pragma unroll
      for (int mm = 32; mm >= 1; mm >>= 1) d += __shfl_xor(d, mm, 64);
      if (lane == 0) denk[w][i] = d;
    } else {
      a[i] = 0.f;
      if (lane == 0) denk[w][i] = 0.f;
    }
  }
  *(float4*)&sm.aT[w][lane][0] = make_float4(a[0], a[1], a[2], a[3]);
  *(float4*)&sm.aT[w][lane][4] = make_float4(a[4], a[5], a[6], a[7]);
  __syncthreads();

  // ---- phase 2: num[i][h] += a[i][slot]*v[jorig(slot)][h] ----
  const int lj = lane >> 5, lh = lane & 31;   // lj: slot-parity, lh*4: h window
  float nr[TI][4];
  #pragma unroll
  for (int i = 0; i < TI; i++) { nr[i][0]=0.f; nr[i][1]=0.f; nr[i][2]=0.f; nr[i][3]=0.f; }
  const unsigned* __restrict__ vb = vph + (size_t)(b << 9) * 64;  // batch base

  if (anyq && wlive) {
    #pragma unroll 4
    for (int js = 0; js < 32; js++) {
      const int j = js * 2 + lj;                 // compacted slot in wave
      const int jr = __shfl(myj, j, 64);         // original j (row gather)
      const uint2 vv = *(const uint2*)(vb + (size_t)jr * 64 + lh * 2);
      const h2v pv0 = BCH(vv.x), pv1 = BCH(vv.y);
      const float v0 = (float)pv0.x, v1 = (float)pv0.y;
      const float v2 = (float)pv1.x, v3 = (float)pv1.y;
      float av[TI];
      { const float4 t0 = *(const float4*)&sm.aT[w][j][0];
        const float4 t1 = *(const float4*)&sm.aT[w][j][4];
        av[0]=t0.x; av[1]=t0.y; av[2]=t0.z; av[3]=t0.w;
        av[4]=t1.x; av[5]=t1.y; av[6]=t1.z; av[7]=t1.w; }
      #pragma unroll
      for (int i = 0; i < TI; i++) {
        nr[i][0] = __builtin_fmaf(av[i], v0, nr[i][0]);
        nr[i][1] = __builtin_fmaf(av[i], v1, nr[i][1]);
        nr[i][2] = __builtin_fmaf(av[i], v2, nr[i][2]);
        nr[i][3] = __builtin_fmaf(av[i], v3, nr[i][3]);
      }
    }
    #pragma unroll
    for (int i = 0; i < TI; i++) {
      #pragma unroll
      for (int k = 0; k < 4; k++) nr[i][k] += __shfl_xor(nr[i][k], 32, 64);
    }
  }

  __syncthreads();   // all aT reads done before numk overwrites the union
  if (lane < 32) {   // lh == lane; both parities hold the folded sum
    #pragma unroll
    for (int i = 0; i < TI; i++)
      *(float4*)&sm.numk[w][i][lane * 4] =
          make_float4(nr[i][0], nr[i][1], nr[i][2], nr[i][3]);
  }
  __syncthreads();

  // ---- cross-wave reduce + normalize + store out directly ----
  const int ii = tid >> 6;              // 0..7 (wave-uniform)
  const int h0 = tid & 63;              // two h per thread: h0, h0+64
  float n0 = 0.f, n1 = 0.f, d = 0.f;
  #pragma unroll
  for (int ww = 0; ww < 8; ww++) {
    n0 += sm.numk[ww][ii][h0];
    n1 += sm.numk[ww][ii][h0 + 64];
    d += denk[ww][ii];
  }
  const float inv = 1.f / fmaxf(d, 2e-15f);
  out[(size_t)(r0 + ii) * H + h0] = n0 * inv;
  out[(size_t)(r0 + ii) * H + h0 + 64] = n1 * inv;
}

extern "C" void kernel_launch(void* const* d_in, const int* in_sizes, int n_in,
                              void* d_out, int out_size, void* d_ws, size_t ws_size,
                              hipStream_t stream)
{
  (void)in_sizes; (void)n_in; (void)out_size; (void)ws_size;
  const float* query  = (const float*)d_in[0];
  const float* key    = (const float*)d_in[1];
  const float* value  = (const float*)d_in[2];
  const int*   q_mask = (const int*)d_in[3];
  const int*   k_mask = (const int*)d_in[4];
  const float* W1     = (const float*)d_in[5];
  const float* b1     = (const float*)d_in[6];
  const float* W2     = (const float*)d_in[7];
  const float* b2     = (const float*)d_in[8];
  float* out = (float*)d_out;

  unsigned* ws  = (unsigned*)d_ws;
  unsigned* qph = ws;                                // [4096][64] half2
  unsigned* kph = ws + (size_t)NROW * 64;            // [4096][64] half2
  unsigned* vph = kph + (size_t)NROW * 64;           // [4096][64] half2
  unsigned* w2h = vph + (size_t)NROW * 64;           // [64] half2

  proj_kernel<<<1280, 256, 0, stream>>>(query, key, value, W1, b1, W2,
                                        qph, kph, vph, w2h);
  attn_kernel<<<512, 512, 0, stream>>>(qph, kph, w2h, vph, q_mask, k_mask,
                                       b2, out);
}